// Round 8
// baseline (491.419 us; speedup 1.0000x reference)
//
#include <hip/hip_runtime.h>
#include <hip/hip_bf16.h>
#include <stdint.h>

// Problem constants
#define L_DIM 4096
#define B_DIM 32
#define H_DIM 512
#define M_DIM (L_DIM * B_DIM)  // 131072 rows of the fused GEMM
#define K_DIM H_DIM            // 512 reduction dim

typedef _Float16 half8 __attribute__((ext_vector_type(8)));
typedef __fp16 fp16x2 __attribute__((ext_vector_type(2)));  // cvt_pkrtz return type
typedef float floatx4 __attribute__((ext_vector_type(4)));

// tanh(x) = 1 - 2/(1 + e^{2x}), via hw exp2 + rcp (~1e-7 abs err, saturates correctly)
__device__ __forceinline__ float tanh_fast(float x) {
  float e = __builtin_amdgcn_exp2f(x * 2.88539008177793f);  // 2*log2(e)
  return 1.0f - 2.0f * __builtin_amdgcn_rcpf(e + 1.0f);
}

__device__ __forceinline__ uint2 pack4(const float4& f) {
  const fp16x2 p0 = __builtin_amdgcn_cvt_pkrtz(f.x, f.y);
  const fp16x2 p1 = __builtin_amdgcn_cvt_pkrtz(f.z, f.w);
  uint2 u;
  u.x = __builtin_bit_cast(unsigned, p0);
  u.y = __builtin_bit_cast(unsigned, p1);
  return u;
}

__device__ __forceinline__ half8 packfrag(const float4& lo, const float4& hi) {
  const uint2 u0 = pack4(lo);
  const uint2 u1 = pack4(hi);
  const uint4 uu = make_uint4(u0.x, u0.y, u1.x, u1.y);
  return __builtin_bit_cast(half8, uu);
}

// async global->LDS DMA: 16B per lane, LDS dest = wave-uniform base + lane*16
__device__ __forceinline__ void gload_lds16(const void* g, void* l) {
  __builtin_amdgcn_global_load_lds(
      (const __attribute__((address_space(1))) void*)g,
      (__attribute__((address_space(3))) void*)l, 16, 0, 0);
}

// ---------------------------------------------------------------------------
// Merged prep (512 threads): blocks [0,64) build W2 (Wk fp16, fragment-packed);
// blocks [64,96) compute q_proj with 4-way K-split + LDS reduce.
// W2 chunk c = ((kt*32 + nc)*4 + q)*16 + l15 holds Wk[k=kt*32+q*8+j][n=nc*16+l15].
__global__ __launch_bounds__(512) void prep_kernel(const float* __restrict__ query,
                                                   const float* __restrict__ W,
                                                   float* __restrict__ qp,
                                                   _Float16* __restrict__ W2) {
  __shared__ float4 qred[512];
  if (blockIdx.x < 64) {
    // ---- wconv: Wk (=W[512:]) -> packed fp16 chunks
    const int t = blockIdx.x * 512 + threadIdx.x;  // [0, 32768) chunk index
    const int l15 = t & 15;
    const int q = (t >> 4) & 3;
    const int nc = (t >> 6) & 31;
    const int kt = t >> 11;
    const int n = nc * 16 + l15;
    const int kbase = H_DIM + kt * 32 + q * 8;  // Wk rows live at W[512 + k]
    half8 h;
#pragma unroll
    for (int j = 0; j < 8; ++j)
      h[j] = (_Float16)W[(size_t)(kbase + j) * H_DIM + n];
    *(half8*)(W2 + (size_t)t * 8) = h;
  } else {
    // ---- qproj: q_proj[b][h] = sum_i query[b][i] * W[i][h], 4-way K-split
    const int b = blockIdx.x - 64;
    const int tid = threadIdx.x;
    const int hx = tid & 127;       // h-column group
    const int ky = tid >> 7;        // K-chunk [0,4)
    const int h = hx * 4;
    const float* qrow = query + b * H_DIM + ky * 128;
    const float* wrow = W + (size_t)(ky * 128) * H_DIM + h;
    float4 acc = make_float4(0.f, 0.f, 0.f, 0.f);
#pragma unroll 8
    for (int i = 0; i < 128; ++i) {
      const float qv = qrow[i];
      const float4 w4 = *(const float4*)(wrow + (size_t)i * H_DIM);
      acc.x += qv * w4.x; acc.y += qv * w4.y;
      acc.z += qv * w4.z; acc.w += qv * w4.w;
    }
    qred[tid] = acc;
    __syncthreads();
    if (ky == 0) {
      const float4 a1 = qred[tid + 128], a2 = qred[tid + 256], a3 = qred[tid + 384];
      acc.x += a1.x + a2.x + a3.x;
      acc.y += a1.y + a2.y + a3.y;
      acc.z += a1.z + a2.z + a3.z;
      acc.w += a1.w + a2.w + a3.w;
      *(float4*)(qp + (size_t)b * H_DIM + h) = acc;
    }
  }
}

// ---------------------------------------------------------------------------
// Fused GEMM + tanh + v-dot, v6: OPERAND SWAP. 64 rows x 512 cols per block,
// 8 waves as 2 row-groups (wr) x 4 col-groups (wc); per wave: 32 rows x 128
// cols, acc[2][8] = 64 VGPR; 2 blocks/CU.
// A (the HBM stream, the bottleneck): read DIRECTLY global->VGPR as MFMA
// fragments, prefetched 1 epoch ahead into registers -- NO barrier in its
// dependency chain, so the HBM stream issues continuously even while waves
// sit at the B barrier. Lanes of a quad cover 16 rows x full 128B lines
// (fully consumed); the 4 col-waves re-read the same 8 KB kt-slice -> L1
// dedups, HBM traffic stays 256 MiB. fp32->fp16 pack: 2 packfrag/wave/kt.
// B (W2, fragment-packed, L2-hot, 3x BW headroom): global_load_lds DMA into
// 2 x 32 KB LDS double-buffer (linear dest = packed source; stride-1
// conflict-free ds_read_b128; zero VGPR cost, no repack). Barriers gate
// ONLY B. Counted vmcnt(4) per kt (A(kt+1) stays in flight across the
// barrier; drains to 0 only at kt=15).
__global__ __launch_bounds__(512, 4) void fused_gemm_kernel(
    const float* __restrict__ key, const _Float16* __restrict__ W2,
    const float* __restrict__ qp, const float* __restrict__ v,
    float* __restrict__ scores) {
  __shared__ __align__(16) char Bs[2 * 32768];  // B double-buffer
  __shared__ float swave[4 * 64];

  const int tid = threadIdx.x;
  const int lane = tid & 63;
  const int wn = tid >> 6;
  const int wr = wn >> 2;         // row-group [0,2)
  const int wc = wn & 3;          // col-group [0,4)
  const int l15 = lane & 15;
  const int quad = lane >> 4;
  const int m0 = blockIdx.x * 64;

  // A fragment sources: lane holds row (wr*32 + fm*16 + l15), k = kt*32+quad*8
  const float* agA = key + (size_t)(m0 + wr * 32 + l15) * K_DIM + quad * 8;
  const float* agB = agA + (size_t)16 * K_DIM;

  // B DMA: per-lane source chunk tid of each 32KB kt-slice; per-wave dest
  const char* wsrc = (const char*)W2 + (size_t)tid * 16;
  char* wdst = Bs + wn * 1024;
  // B fragment reads: byte (kt&1)*32768 + (wc*8+fn)*1024 + quad*256 + l15*16
  const char* rbase = Bs + wc * 8192 + quad * 256 + l15 * 16;

  floatx4 acc[2][8];
#pragma unroll
  for (int fm = 0; fm < 2; ++fm)
#pragma unroll
    for (int fn = 0; fn < 8; ++fn) acc[fm][fn] = (floatx4)0.0f;

  // prologue: A(0) -> regs; DMA B(0) -> buf0
  float4 cA0 = *(const float4*)(agA);
  float4 cA1 = *(const float4*)(agA + 4);
  float4 cB0 = *(const float4*)(agB);
  float4 cB1 = *(const float4*)(agB + 4);
#pragma unroll
  for (int i = 0; i < 4; ++i)
    gload_lds16(wsrc + i * 8192, wdst + i * 8192);

#pragma unroll
  for (int kt = 0; kt < 16; ++kt) {
    // issue A(kt+1) BEFORE the wait: stays in flight across the barrier
    float4 nA0, nA1, nB0, nB1;
    if (kt < 15) {
      nA0 = *(const float4*)(agA + (kt + 1) * 32);
      nA1 = *(const float4*)(agA + (kt + 1) * 32 + 4);
      nB0 = *(const float4*)(agB + (kt + 1) * 32);
      nB1 = *(const float4*)(agB + (kt + 1) * 32 + 4);
    }
    __builtin_amdgcn_sched_barrier(0);
    // retire DMA(kt) (and the already-consumed older A): 4 newest = A(kt+1)
    if (kt < 15) asm volatile("s_waitcnt vmcnt(4)" ::: "memory");
    else         asm volatile("s_waitcnt vmcnt(0)" ::: "memory");
    __builtin_amdgcn_sched_barrier(0);
    __builtin_amdgcn_s_barrier();   // all waves' DMA(kt) landed
    __builtin_amdgcn_sched_barrier(0);

    // DMA B(kt+1) into the other buffer (safe: its readers passed barrier kt)
    if (kt < 15) {
      const char* s = wsrc + (size_t)(kt + 1) * 32768;
      char* d = wdst + ((kt + 1) & 1) * 32768;
#pragma unroll
      for (int i = 0; i < 4; ++i)
        gload_lds16(s + i * 8192, d + i * 8192);
    }

    // current A fragments (regs loaded last epoch)
    const half8 avA = packfrag(cA0, cA1);
    const half8 avB = packfrag(cB0, cB1);

    // B fragments fn=0..3, then MFMA; then fn=4..7 (chunked: live B = 16 VGPR)
    const char* rb = rbase + (kt & 1) * 32768;
    {
      const half8 b0 = *(const half8*)(rb + 0 * 1024);
      const half8 b1 = *(const half8*)(rb + 1 * 1024);
      const half8 b2 = *(const half8*)(rb + 2 * 1024);
      const half8 b3 = *(const half8*)(rb + 3 * 1024);
      acc[0][0] = __builtin_amdgcn_mfma_f32_16x16x32_f16(avA, b0, acc[0][0], 0, 0, 0);
      acc[0][1] = __builtin_amdgcn_mfma_f32_16x16x32_f16(avA, b1, acc[0][1], 0, 0, 0);
      acc[0][2] = __builtin_amdgcn_mfma_f32_16x16x32_f16(avA, b2, acc[0][2], 0, 0, 0);
      acc[0][3] = __builtin_amdgcn_mfma_f32_16x16x32_f16(avA, b3, acc[0][3], 0, 0, 0);
      acc[1][0] = __builtin_amdgcn_mfma_f32_16x16x32_f16(avB, b0, acc[1][0], 0, 0, 0);
      acc[1][1] = __builtin_amdgcn_mfma_f32_16x16x32_f16(avB, b1, acc[1][1], 0, 0, 0);
      acc[1][2] = __builtin_amdgcn_mfma_f32_16x16x32_f16(avB, b2, acc[1][2], 0, 0, 0);
      acc[1][3] = __builtin_amdgcn_mfma_f32_16x16x32_f16(avB, b3, acc[1][3], 0, 0, 0);
    }
    {
      const half8 b4 = *(const half8*)(rb + 4 * 1024);
      const half8 b5 = *(const half8*)(rb + 5 * 1024);
      const half8 b6 = *(const half8*)(rb + 6 * 1024);
      const half8 b7 = *(const half8*)(rb + 7 * 1024);
      acc[0][4] = __builtin_amdgcn_mfma_f32_16x16x32_f16(avA, b4, acc[0][4], 0, 0, 0);
      acc[0][5] = __builtin_amdgcn_mfma_f32_16x16x32_f16(avA, b5, acc[0][5], 0, 0, 0);
      acc[0][6] = __builtin_amdgcn_mfma_f32_16x16x32_f16(avA, b6, acc[0][6], 0, 0, 0);
      acc[0][7] = __builtin_amdgcn_mfma_f32_16x16x32_f16(avA, b7, acc[0][7], 0, 0, 0);
      acc[1][4] = __builtin_amdgcn_mfma_f32_16x16x32_f16(avB, b4, acc[1][4], 0, 0, 0);
      acc[1][5] = __builtin_amdgcn_mfma_f32_16x16x32_f16(avB, b5, acc[1][5], 0, 0, 0);
      acc[1][6] = __builtin_amdgcn_mfma_f32_16x16x32_f16(avB, b6, acc[1][6], 0, 0, 0);
      acc[1][7] = __builtin_amdgcn_mfma_f32_16x16x32_f16(avB, b7, acc[1][7], 0, 0, 0);
    }
    // rotate A prefetch
    cA0 = nA0; cA1 = nA1; cB0 = nB0; cB1 = nB1;
  }

  // Epilogue: score[m] = sum_n v[n] * tanh(qp[m&31][n] + kproj[m][n])
  // C/D layout: col = lane&15, row = quad*4 + reg (verified: passes)
  float vv[8];
#pragma unroll
  for (int fn = 0; fn < 8; ++fn) vv[fn] = v[wc * 128 + fn * 16 + l15];

#pragma unroll
  for (int fm = 0; fm < 2; ++fm) {
#pragma unroll
    for (int r = 0; r < 4; ++r) {
      const int mrow = wr * 32 + fm * 16 + quad * 4 + r;
      const float* qrow = qp + (size_t)((m0 + mrow) & 31) * H_DIM;
      float rs = 0.f;
#pragma unroll
      for (int fn = 0; fn < 8; ++fn) {
        const int n = wc * 128 + fn * 16 + l15;
        const float x = qrow[n] + acc[fm][fn][r];
        rs += vv[fn] * tanh_fast(x);
      }
      rs += __shfl_xor(rs, 1);
      rs += __shfl_xor(rs, 2);
      rs += __shfl_xor(rs, 4);
      rs += __shfl_xor(rs, 8);
      if (l15 == 0) swave[wc * 64 + mrow] = rs;
    }
  }
  __syncthreads();
  if (tid < 64) {
    const float s = swave[tid] + swave[64 + tid] + swave[128 + tid] + swave[192 + tid];
    const int m = m0 + tid;  // m = l*32 + b
    scores[(size_t)(m & 31) * L_DIM + (m >> 5)] = s;  // transposed: [b][l]
  }
}

// ---------------------------------------------------------------------------
// softmax over l per b; scores already [b][l]; out[b][l] — fully coalesced.
// Wave shfl reductions: 2 barriers instead of 16.
__global__ __launch_bounds__(256) void softmax_kernel(const float* __restrict__ scores,
                                                      float* __restrict__ out) {
  const int b = blockIdx.x;
  const int t = threadIdx.x;
  const int lane = t & 63;
  const int w = t >> 6;
  __shared__ float redm[4], reds[4];
  const float* srow = scores + (size_t)b * L_DIM;
  float s[16];
#pragma unroll
  for (int i = 0; i < 16; ++i) s[i] = srow[t + i * 256];
  float mx = s[0];
#pragma unroll
  for (int i = 1; i < 16; ++i) mx = fmaxf(mx, s[i]);
#pragma unroll
  for (int off = 1; off < 64; off <<= 1) mx = fmaxf(mx, __shfl_xor(mx, off));
  if (lane == 0) redm[w] = mx;
  __syncthreads();
  mx = fmaxf(fmaxf(redm[0], redm[1]), fmaxf(redm[2], redm[3]));
  float sum = 0.f;
#pragma unroll
  for (int i = 0; i < 16; ++i) {
    s[i] = __builtin_amdgcn_exp2f((s[i] - mx) * 1.44269504f);
    sum += s[i];
  }
#pragma unroll
  for (int off = 1; off < 64; off <<= 1) sum += __shfl_xor(sum, off);
  if (lane == 0) reds[w] = sum;
  __syncthreads();
  const float inv = 1.0f / (reds[0] + reds[1] + reds[2] + reds[3]);
#pragma unroll
  for (int i = 0; i < 16; ++i) out[(size_t)b * L_DIM + t + i * 256] = s[i] * inv;
}

// ---------------------------------------------------------------------------
extern "C" void kernel_launch(void* const* d_in, const int* in_sizes, int n_in,
                              void* d_out, int out_size, void* d_ws, size_t ws_size,
                              hipStream_t stream) {
  const float* query = (const float*)d_in[0];
  const float* key   = (const float*)d_in[1];
  const float* W     = (const float*)d_in[2];
  const float* v     = (const float*)d_in[3];
  float* out = (float*)d_out;

  char* ws = (char*)d_ws;
  float* qp       = (float*)ws;                        // 32*512*4   = 64 KB
  float* scores   = (float*)(ws + 65536);              // 131072*4   = 512 KB
  _Float16* W2    = (_Float16*)(ws + 65536 + 524288);  // 512*512*2  = 512 KB

  prep_kernel<<<96, 512, 0, stream>>>(query, W, qp, W2);
  fused_gemm_kernel<<<M_DIM / 64, 512, 0, stream>>>(key, W2, qp, v, scores);
  softmax_kernel<<<B_DIM, 256, 0, stream>>>(scores, out);
}